// Round 1
// baseline (1923.640 us; speedup 1.0000x reference)
//
#include <hip/hip_runtime.h>

// Problem constants
#define BATCH 8
#define CIN   128
#define HH    112
#define WW    112
#define COUT  256
#define KOFF  18          // 2*K*K offset channels
#define HW    (HH*WW)     // 12544
#define NPIX  (BATCH*HW)  // 100352

// ---------------------------------------------------------------------------
// Kernel 1: offset conv.  out[b,c,y,x] = bias[c] + sum_{ci,dy,dx} w[c,ci,dy,dx]*x[b,ci,y+dy-1,x+dx-1]
// One thread per pixel computes all 18 output channels; weights staged in LDS
// in ci-chunks of 32 (18*32*9*4 = 20.7 KB).
// ---------------------------------------------------------------------------
__global__ __launch_bounds__(256) void offset_conv_kernel(
    const float* __restrict__ x, const float* __restrict__ ow,
    const float* __restrict__ ob, float* __restrict__ offset_out)
{
    __shared__ float wlds[KOFF][32][9];
    const int tid = threadIdx.x;
    const int p   = blockIdx.x * 256 + tid;   // exact: 392*256 == NPIX
    const int b   = p / HW;
    const int rem = p % HW;
    const int y   = rem / WW;
    const int xx  = rem % WW;

    float acc[KOFF];
#pragma unroll
    for (int c = 0; c < KOFF; ++c) acc[c] = 0.f;

    for (int cb = 0; cb < CIN; cb += 32) {
        __syncthreads();
        for (int i = tid; i < KOFF * 32 * 9; i += 256) {
            int c  = i / 288;        // 32*9
            int r  = i % 288;
            int ci = r / 9;
            int t  = r % 9;
            wlds[c][ci][t] = ow[((size_t)c * CIN + cb + ci) * 9 + t];
        }
        __syncthreads();

        for (int ci = 0; ci < 32; ++ci) {
            const float* xp = x + ((size_t)(b * CIN + cb + ci)) * HW;
            float v[9];
#pragma unroll
            for (int dy = 0; dy < 3; ++dy) {
                int  yy  = y + dy - 1;
                bool yok = (unsigned)yy < HH;
#pragma unroll
                for (int dx = 0; dx < 3; ++dx) {
                    int  xw = xx + dx - 1;
                    bool ok = yok && ((unsigned)xw < WW);
                    v[dy * 3 + dx] = ok ? xp[yy * WW + xw] : 0.f;
                }
            }
#pragma unroll
            for (int c = 0; c < KOFF; ++c) {
                float a = acc[c];
#pragma unroll
                for (int t = 0; t < 9; ++t) a += v[t] * wlds[c][ci][t];
                acc[c] = a;
            }
        }
    }
#pragma unroll
    for (int c = 0; c < KOFF; ++c)
        offset_out[((size_t)(b * KOFF + c)) * HW + rem] = acc[c] + ob[c];
}

// ---------------------------------------------------------------------------
// Kernel 2: deformable bilinear sampling, summed over the 9 sample points.
// sampled[b,ci,y,x] = sum_{s=0..8} bilinear(x[b,ci], y+ky-1+off_y, x+kx-1+off_x)
// Block: 256 threads = 64 pixels x 4 channel-lanes. Each thread precomputes
// its pixel's 36 (clipped index, masked weight) pairs in registers, then
// iterates 32 channels (ci = lane_group + 4*k).
// ---------------------------------------------------------------------------
__global__ __launch_bounds__(256) void sample_kernel(
    const float* __restrict__ x, const float* __restrict__ offset,
    float* __restrict__ sampled)
{
    const int tid = threadIdx.x;
    const int px  = tid & 63;
    const int cig = tid >> 6;                 // 0..3
    const int p   = blockIdx.x * 64 + px;     // exact: 1568*64 == NPIX
    const int b   = p / HW;
    const int rem = p % HW;
    const int y   = rem / WW;
    const int xx  = rem % WW;

    int   idx[9][4];
    float wt[9][4];
    const float* offp = offset + (size_t)b * KOFF * HW + rem;
#pragma unroll
    for (int s = 0; s < 9; ++s) {
        const int ky = s / 3, kx = s % 3;
        const float oy = offp[(size_t)s * HW];
        const float ox = offp[(size_t)(9 + s) * HW];
        const float sy = (float)(y + ky - 1) + oy;
        const float sx = (float)(xx + kx - 1) + ox;
        const float y0f = floorf(sy), x0f = floorf(sx);
        const int   y0 = (int)y0f, x0 = (int)x0f;
        const float wy1 = sy - y0f, wx1 = sx - x0f;
        const float wy0 = 1.f - wy1, wx0 = 1.f - wx1;
        const int y0c = min(max(y0, 0), HH - 1), y1c = min(max(y0 + 1, 0), HH - 1);
        const int x0c = min(max(x0, 0), WW - 1), x1c = min(max(x0 + 1, 0), WW - 1);
        const bool vy0 = (unsigned)y0 < HH, vy1 = (unsigned)(y0 + 1) < HH;
        const bool vx0 = (unsigned)x0 < WW, vx1 = (unsigned)(x0 + 1) < WW;
        idx[s][0] = y0c * WW + x0c; wt[s][0] = (vy0 && vx0) ? wy0 * wx0 : 0.f;
        idx[s][1] = y0c * WW + x1c; wt[s][1] = (vy0 && vx1) ? wy0 * wx1 : 0.f;
        idx[s][2] = y1c * WW + x0c; wt[s][2] = (vy1 && vx0) ? wy1 * wx0 : 0.f;
        idx[s][3] = y1c * WW + x1c; wt[s][3] = (vy1 && vx1) ? wy1 * wx1 : 0.f;
    }

    const float* xb = x + (size_t)b * CIN * HW;
    float*       sb = sampled + (size_t)b * CIN * HW + rem;
    for (int ci = cig; ci < CIN; ci += 4) {
        const float* xp = xb + (size_t)ci * HW;
        float a = 0.f;
#pragma unroll
        for (int s = 0; s < 9; ++s) {
            a += xp[idx[s][0]] * wt[s][0]
               + xp[idx[s][1]] * wt[s][1]
               + xp[idx[s][2]] * wt[s][2]
               + xp[idx[s][3]] * wt[s][3];
        }
        sb[(size_t)ci * HW] = a;
    }
}

// ---------------------------------------------------------------------------
// Kernel 3: main 3x3 conv over `sampled` (zero pad 1), Cout=256.
// Thread = 1 pixel x 8 couts. Weights for the block's 8 couts staged in LDS
// as [ci][tap][co8] (36.9 KB) -> broadcast ds_read_b128 reads, no conflicts.
// ---------------------------------------------------------------------------
#define COG 8
__global__ __launch_bounds__(256) void conv_kernel(
    const float* __restrict__ sampled, const float* __restrict__ cw,
    float* __restrict__ out)
{
    __shared__ float wlds[CIN][9][COG];   // 128*9*8*4 = 36864 B
    const int tid = threadIdx.x;
    const int p   = blockIdx.x * 256 + tid;  // exact: 392*256 == NPIX
    const int b   = p / HW;
    const int rem = p % HW;
    const int y   = rem / WW;
    const int xx  = rem % WW;
    const int cog = blockIdx.y;              // 0..31

    for (int i = tid; i < CIN * 9 * COG; i += 256) {
        int j  = i & 7;
        int t  = (i >> 3) % 9;
        int ci = i / 72;
        wlds[ci][t][j] = cw[((size_t)(cog * COG + j) * CIN + ci) * 9 + t];
    }
    __syncthreads();

    float acc[COG];
#pragma unroll
    for (int j = 0; j < COG; ++j) acc[j] = 0.f;

    const float* sp = sampled + (size_t)b * CIN * HW;
    for (int ci = 0; ci < CIN; ++ci) {
        const float* spp = sp + (size_t)ci * HW;
        float v[9];
#pragma unroll
        for (int dy = 0; dy < 3; ++dy) {
            int  yy  = y + dy - 1;
            bool yok = (unsigned)yy < HH;
#pragma unroll
            for (int dx = 0; dx < 3; ++dx) {
                int  xw = xx + dx - 1;
                bool ok = yok && ((unsigned)xw < WW);
                v[dy * 3 + dx] = ok ? spp[yy * WW + xw] : 0.f;
            }
        }
#pragma unroll
        for (int t = 0; t < 9; ++t) {
            float vv = v[t];
#pragma unroll
            for (int j = 0; j < COG; ++j) acc[j] += vv * wlds[ci][t][j];
        }
    }
#pragma unroll
    for (int j = 0; j < COG; ++j)
        out[((size_t)(b * COUT + cog * COG + j)) * HW + rem] = acc[j];
}

// ---------------------------------------------------------------------------
extern "C" void kernel_launch(void* const* d_in, const int* in_sizes, int n_in,
                              void* d_out, int out_size, void* d_ws, size_t ws_size,
                              hipStream_t stream)
{
    const float* x  = (const float*)d_in[0];   // (8,128,112,112)
    const float* ow = (const float*)d_in[1];   // (18,128,3,3)
    const float* ob = (const float*)d_in[2];   // (18,)
    const float* cw = (const float*)d_in[3];   // (256,128,3,3)
    float* out = (float*)d_out;                // (8,256,112,112)

    // workspace: offset (7.2 MB) then sampled (51.4 MB) = 58.6 MB total
    float* offset  = (float*)d_ws;
    float* sampled = offset + (size_t)BATCH * KOFF * HW;

    offset_conv_kernel<<<dim3(NPIX / 256), dim3(256), 0, stream>>>(x, ow, ob, offset);
    sample_kernel<<<dim3(NPIX / 64), dim3(256), 0, stream>>>(x, offset, sampled);
    conv_kernel<<<dim3(NPIX / 256, COUT / COG), dim3(256), 0, stream>>>(sampled, cw, out);
}

// Round 2
// 885.206 us; speedup vs baseline: 2.1731x; 2.1731x over previous
//
#include <hip/hip_runtime.h>

// Problem constants
#define BATCH 8
#define CIN   128
#define HH    112
#define WW    112
#define COUT  256
#define KOFF  18          // 2*K*K offset channels
#define HW    (HH*WW)     // 12544
#define NPIX  (BATCH*HW)  // 100352

typedef __attribute__((ext_vector_type(8))) short short8;
typedef __attribute__((ext_vector_type(4))) float f32x4;

__device__ __forceinline__ unsigned short f2bf(float f) {
    union { float f; unsigned u; } v; v.f = f;
    unsigned r = v.u + 0x7fffu + ((v.u >> 16) & 1u);   // round-to-nearest-even
    return (unsigned short)(r >> 16);
}

// ---------------------------------------------------------------------------
// Kernel 0: weight convert+transpose: wt[co][t*128+ci] = bf16(cw[co][ci][t])
// ---------------------------------------------------------------------------
__global__ __launch_bounds__(256) void wconvert_kernel(
    const float* __restrict__ cw, unsigned short* __restrict__ wt)
{
    const int i  = blockIdx.x * 256 + threadIdx.x;   // 1152 blocks * 256 == 294912 exact
    const int co = i / 1152;
    const int k  = i % 1152;
    const int t  = k >> 7;
    const int ci = k & 127;
    wt[i] = f2bf(cw[((size_t)(co * CIN + ci)) * 9 + t]);
}

// ---------------------------------------------------------------------------
// Kernel 1: offset conv (fp32, unchanged from round 1 — small)
// ---------------------------------------------------------------------------
__global__ __launch_bounds__(256) void offset_conv_kernel(
    const float* __restrict__ x, const float* __restrict__ ow,
    const float* __restrict__ ob, float* __restrict__ offset_out)
{
    __shared__ float wlds[KOFF][32][9];
    const int tid = threadIdx.x;
    const int p   = blockIdx.x * 256 + tid;
    const int b   = p / HW;
    const int rem = p % HW;
    const int y   = rem / WW;
    const int xx  = rem % WW;

    float acc[KOFF];
#pragma unroll
    for (int c = 0; c < KOFF; ++c) acc[c] = 0.f;

    for (int cb = 0; cb < CIN; cb += 32) {
        __syncthreads();
        for (int i = tid; i < KOFF * 32 * 9; i += 256) {
            int c  = i / 288;
            int r  = i % 288;
            int ci = r / 9;
            int t  = r % 9;
            wlds[c][ci][t] = ow[((size_t)c * CIN + cb + ci) * 9 + t];
        }
        __syncthreads();

        for (int ci = 0; ci < 32; ++ci) {
            const float* xp = x + ((size_t)(b * CIN + cb + ci)) * HW;
            float v[9];
#pragma unroll
            for (int dy = 0; dy < 3; ++dy) {
                int  yy  = y + dy - 1;
                bool yok = (unsigned)yy < HH;
#pragma unroll
                for (int dx = 0; dx < 3; ++dx) {
                    int  xw = xx + dx - 1;
                    bool ok = yok && ((unsigned)xw < WW);
                    v[dy * 3 + dx] = ok ? xp[yy * WW + xw] : 0.f;
                }
            }
#pragma unroll
            for (int c = 0; c < KOFF; ++c) {
                float a = acc[c];
#pragma unroll
                for (int t = 0; t < 9; ++t) a += v[t] * wlds[c][ci][t];
                acc[c] = a;
            }
        }
    }
#pragma unroll
    for (int c = 0; c < KOFF; ++c)
        offset_out[((size_t)(b * KOFF + c)) * HW + rem] = acc[c] + ob[c];
}

// ---------------------------------------------------------------------------
// Kernel 2: deformable sampling -> NHWC bf16 via LDS transpose.
// Block: 64 px x 4 ci-groups; thread owns ci-pairs {2g,2g+1}+8k (k=0..15),
// gathers stay wave-coherent (64 consecutive pixels, same ci plane).
// LDS tile 64px x 130 bf16 (65-word row stride -> 2-way-free banks), then
// coalesced 64B NHWC stores.
// ---------------------------------------------------------------------------
__global__ __launch_bounds__(256) void sample_kernel(
    const float* __restrict__ x, const float* __restrict__ offset,
    unsigned short* __restrict__ sampled)
{
    __shared__ unsigned int sm[64 * 65];   // 16.6 KB
    const int tid = threadIdx.x;
    const int px  = tid & 63;
    const int cig = tid >> 6;                 // 0..3
    const int p   = blockIdx.x * 64 + px;     // 1568 blocks * 64 == NPIX
    const int b   = p / HW;
    const int rem = p % HW;
    const int y   = rem / WW;
    const int xx  = rem % WW;

    int   idx[9][4];
    float wt[9][4];
    const float* offp = offset + (size_t)b * KOFF * HW + rem;
#pragma unroll
    for (int s = 0; s < 9; ++s) {
        const int ky = s / 3, kx = s % 3;
        const float oy = offp[(size_t)s * HW];
        const float ox = offp[(size_t)(9 + s) * HW];
        const float sy = (float)(y + ky - 1) + oy;
        const float sx = (float)(xx + kx - 1) + ox;
        const float y0f = floorf(sy), x0f = floorf(sx);
        const int   y0 = (int)y0f, x0 = (int)x0f;
        const float wy1 = sy - y0f, wx1 = sx - x0f;
        const float wy0 = 1.f - wy1, wx0 = 1.f - wx1;
        const int y0c = min(max(y0, 0), HH - 1), y1c = min(max(y0 + 1, 0), HH - 1);
        const int x0c = min(max(x0, 0), WW - 1), x1c = min(max(x0 + 1, 0), WW - 1);
        const bool vy0 = (unsigned)y0 < HH, vy1 = (unsigned)(y0 + 1) < HH;
        const bool vx0 = (unsigned)x0 < WW, vx1 = (unsigned)(x0 + 1) < WW;
        idx[s][0] = y0c * WW + x0c; wt[s][0] = (vy0 && vx0) ? wy0 * wx0 : 0.f;
        idx[s][1] = y0c * WW + x1c; wt[s][1] = (vy0 && vx1) ? wy0 * wx1 : 0.f;
        idx[s][2] = y1c * WW + x0c; wt[s][2] = (vy1 && vx0) ? wy1 * wx0 : 0.f;
        idx[s][3] = y1c * WW + x1c; wt[s][3] = (vy1 && vx1) ? wy1 * wx1 : 0.f;
    }

    const float* xb = x + (size_t)b * CIN * HW;
    const int c0 = 2 * cig;
    for (int k = 0; k < 16; ++k) {
        const int ci = c0 + 8 * k;
        const float* xp0 = xb + (size_t)ci * HW;
        const float* xp1 = xp0 + HW;
        float a0 = 0.f, a1 = 0.f;
#pragma unroll
        for (int s = 0; s < 9; ++s) {
            a0 += xp0[idx[s][0]] * wt[s][0] + xp0[idx[s][1]] * wt[s][1]
                + xp0[idx[s][2]] * wt[s][2] + xp0[idx[s][3]] * wt[s][3];
            a1 += xp1[idx[s][0]] * wt[s][0] + xp1[idx[s][1]] * wt[s][1]
                + xp1[idx[s][2]] * wt[s][2] + xp1[idx[s][3]] * wt[s][3];
        }
        sm[px * 65 + (ci >> 1)] = (unsigned)f2bf(a0) | ((unsigned)f2bf(a1) << 16);
    }
    __syncthreads();

    // coalesced NHWC write-out: thread = (row=tid>>2, chunk=tid&3) -> 64 B
    const int row = tid >> 2, chunk = tid & 3;
    unsigned int u[16];
#pragma unroll
    for (int c = 0; c < 16; ++c) u[c] = sm[row * 65 + chunk * 16 + c];
    unsigned short* gp = sampled + ((size_t)(blockIdx.x * 64 + row)) * 128 + chunk * 32;
    uint4* gv = (uint4*)gp;
#pragma unroll
    for (int j = 0; j < 4; ++j) {
        uint4 t; t.x = u[4*j]; t.y = u[4*j+1]; t.z = u[4*j+2]; t.w = u[4*j+3];
        gv[j] = t;
    }
}

// ---------------------------------------------------------------------------
// Kernel 3: implicit-GEMM 3x3 conv via bf16 MFMA.
// M=pixels (tile 128), N=couts (tile 128), K=9 taps x 128 ci (BK=64).
// A rows: NHWC sampled at tap-shifted pixel (zero-masked at borders).
// B rows: pre-transposed weights wt[co][t*128+ci].
// 4 waves, each 64x64 = 4x4 frags of mfma_f32_16x16x32_bf16.
// ---------------------------------------------------------------------------
#define BK   64
#define LDR  (BK + 8)     // LDS row stride (elements): 144 B, 16B-aligned, conflict-free frags
__global__ __launch_bounds__(256) void conv_mfma_kernel(
    const unsigned short* __restrict__ sampled, const unsigned short* __restrict__ wt,
    float* __restrict__ out)
{
    __shared__ __align__(16) unsigned short As[128 * LDR];   // 18.4 KB
    __shared__ __align__(16) unsigned short Bs[128 * LDR];   // 18.4 KB

    const int tid = threadIdx.x;
    const int mb  = blockIdx.x;          // 0..783 (98 per image)
    const int b   = mb / 98;
    const int p0  = (mb % 98) * 128;     // pixel base within image
    const int n0  = blockIdx.y * 128;    // cout base

    // staging mapping: thread i -> row i>>1, 64B half (i&1)
    const int srow  = tid >> 1;          // 0..127
    const int shalf = (tid & 1) * 32;    // element offset (32 bf16 = 64 B)
    const int pp  = p0 + srow;
    const int py  = pp / WW;
    const int pxx = pp % WW;

    const unsigned short* sb   = sampled + (size_t)b * HW * 128;
    const unsigned short* wrow = wt + (size_t)(n0 + srow) * 1152 + shalf;

    const int lane = tid & 63;
    const int wave = tid >> 6;
    const int wm   = (wave & 1) * 64;
    const int wn   = (wave >> 1) * 64;
    const int col  = lane & 15;
    const int quad = lane >> 4;

    f32x4 acc[4][4];
#pragma unroll
    for (int i = 0; i < 4; ++i)
#pragma unroll
        for (int j = 0; j < 4; ++j) acc[i][j] = (f32x4)0.f;

    for (int t = 0; t < 9; ++t) {
        const int dy = t / 3 - 1, dx = t % 3 - 1;
        const bool valid = ((unsigned)(py + dy) < HH) && ((unsigned)(pxx + dx) < WW);
        int q = pp + dy * WW + dx;
        q = min(max(q, 0), HW - 1);
        const unsigned short* arow = sb + (size_t)q * 128 + shalf;

        for (int ci0 = 0; ci0 < 128; ci0 += BK) {
            __syncthreads();
            // stage A (64 B per thread)
            {
                const uint4* src = (const uint4*)(arow + ci0);
                uint4* dst = (uint4*)(As + srow * LDR + shalf);
#pragma unroll
                for (int j = 0; j < 4; ++j) {
                    uint4 v = src[j];
                    if (!valid) { v.x = 0; v.y = 0; v.z = 0; v.w = 0; }
                    dst[j] = v;
                }
            }
            // stage B (64 B per thread)
            {
                const uint4* src = (const uint4*)(wrow + t * 128 + ci0);
                uint4* dst = (uint4*)(Bs + srow * LDR + shalf);
#pragma unroll
                for (int j = 0; j < 4; ++j) dst[j] = src[j];
            }
            __syncthreads();

#pragma unroll
            for (int kk = 0; kk < BK; kk += 32) {
                short8 af[4], bf[4];
#pragma unroll
                for (int f = 0; f < 4; ++f)
                    af[f] = *(const short8*)(As + (wm + f * 16 + col) * LDR + kk + quad * 8);
#pragma unroll
                for (int f = 0; f < 4; ++f)
                    bf[f] = *(const short8*)(Bs + (wn + f * 16 + col) * LDR + kk + quad * 8);
#pragma unroll
                for (int fm = 0; fm < 4; ++fm)
#pragma unroll
                    for (int fn = 0; fn < 4; ++fn)
                        acc[fm][fn] = __builtin_amdgcn_mfma_f32_16x16x32_bf16(
                            af[fm], bf[fn], acc[fm][fn], 0, 0, 0);
            }
        }
    }

    // epilogue: D row = pixel = quad*4+reg, col = cout
#pragma unroll
    for (int fm = 0; fm < 4; ++fm) {
        const int pix = p0 + wm + fm * 16 + quad * 4;
#pragma unroll
        for (int fn = 0; fn < 4; ++fn) {
            const int co = n0 + wn + fn * 16 + col;
            float* op = out + ((size_t)(b * COUT + co)) * HW + pix;
            *(f32x4*)op = acc[fm][fn];
        }
    }
}

// ---------------------------------------------------------------------------
extern "C" void kernel_launch(void* const* d_in, const int* in_sizes, int n_in,
                              void* d_out, int out_size, void* d_ws, size_t ws_size,
                              hipStream_t stream)
{
    const float* x  = (const float*)d_in[0];   // (8,128,112,112)
    const float* ow = (const float*)d_in[1];   // (18,128,3,3)
    const float* ob = (const float*)d_in[2];   // (18,)
    const float* cw = (const float*)d_in[3];   // (256,128,3,3)
    float* out = (float*)d_out;                // (8,256,112,112)

    // workspace layout (bytes): offset fp32 7.2MB | sampled bf16 NHWC 25.7MB | wt bf16 0.6MB
    float*          offset  = (float*)d_ws;
    unsigned short* sampled = (unsigned short*)(offset + (size_t)BATCH * KOFF * HW);
    unsigned short* wtb     = sampled + (size_t)BATCH * HW * 128;

    wconvert_kernel<<<dim3(1152), dim3(256), 0, stream>>>(cw, wtb);
    offset_conv_kernel<<<dim3(NPIX / 256), dim3(256), 0, stream>>>(x, ow, ob, offset);
    sample_kernel<<<dim3(NPIX / 64), dim3(256), 0, stream>>>(x, offset, sampled);
    conv_mfma_kernel<<<dim3(784, 2), dim3(256), 0, stream>>>(sampled, wtb, out);
}

// Round 3
// 542.708 us; speedup vs baseline: 3.5445x; 1.6311x over previous
//
#include <hip/hip_runtime.h>

// Problem constants
#define BATCH 8
#define CIN   128
#define HH    112
#define WW    112
#define COUT  256
#define KOFF  18          // 2*K*K offset channels
#define HW    (HH*WW)     // 12544
#define NPIX  (BATCH*HW)  // 100352

typedef __attribute__((ext_vector_type(8))) short short8;
typedef __attribute__((ext_vector_type(4))) float f32x4;

__device__ __forceinline__ unsigned short f2bf(float f) {
    union { float f; unsigned u; } v; v.f = f;
    unsigned r = v.u + 0x7fffu + ((v.u >> 16) & 1u);   // round-to-nearest-even
    return (unsigned short)(r >> 16);
}
__device__ __forceinline__ float bflo(unsigned u) {
    union { unsigned u; float f; } v; v.u = u << 16; return v.f;
}
__device__ __forceinline__ float bfhi(unsigned u) {
    union { unsigned u; float f; } v; v.u = u & 0xffff0000u; return v.f;
}

// ---------------------------------------------------------------------------
// Kernel 0a: weight convert+transpose: wt[co][t*128+ci] = bf16(cw[co][ci][t])
// ---------------------------------------------------------------------------
__global__ __launch_bounds__(256) void wconvert_kernel(
    const float* __restrict__ cw, unsigned short* __restrict__ wt)
{
    const int i  = blockIdx.x * 256 + threadIdx.x;   // 1152*256 == 294912 exact
    const int co = i / 1152;
    const int k  = i % 1152;
    const int t  = k >> 7;
    const int ci = k & 127;
    wt[i] = f2bf(cw[((size_t)(co * CIN + ci)) * 9 + t]);
}

// ---------------------------------------------------------------------------
// Kernel 0b: x NCHW fp32 -> NHWC bf16 (xh[p][128]) via LDS transpose.
// Block = 64 pixels x 128 channels; coalesced plane reads, coalesced row writes.
// ---------------------------------------------------------------------------
__global__ __launch_bounds__(256) void nhwc_kernel(
    const float* __restrict__ x, unsigned short* __restrict__ xh)
{
    __shared__ unsigned int sm[64 * 65];
    const int tid = threadIdx.x;
    const int px  = tid & 63;
    const int cig = tid >> 6;
    const int p0  = blockIdx.x * 64;          // 1568 blocks; blocks never straddle b
    const int b   = p0 / HW;
    const int rem0 = p0 % HW;
    const float* xb = x + (size_t)b * CIN * HW + rem0 + px;

    const int c0 = 2 * cig;
#pragma unroll
    for (int k = 0; k < 16; ++k) {
        const int ci = c0 + 8 * k;            // even ci in [0,126]
        const float a0 = xb[(size_t)ci * HW];
        const float a1 = xb[(size_t)(ci + 1) * HW];
        sm[px * 65 + (ci >> 1)] = (unsigned)f2bf(a0) | ((unsigned)f2bf(a1) << 16);
    }
    __syncthreads();

    const int row = tid >> 2, chunk = tid & 3;
    unsigned int u[16];
#pragma unroll
    for (int c = 0; c < 16; ++c) u[c] = sm[row * 65 + chunk * 16 + c];
    uint4* gv = (uint4*)(xh + ((size_t)(p0 + row)) * 128 + chunk * 32);
#pragma unroll
    for (int j = 0; j < 4; ++j) {
        uint4 t; t.x = u[4*j]; t.y = u[4*j+1]; t.z = u[4*j+2]; t.w = u[4*j+3];
        gv[j] = t;
    }
}

// ---------------------------------------------------------------------------
// Kernel 1: offset conv (fp32 NCHW x). Output: packed bf16 (oy,ox) pairs
// po[p*9+s] = pack(offset_y[s], offset_x[s]) incl. bias.
// ---------------------------------------------------------------------------
__global__ __launch_bounds__(256) void offset_conv_kernel(
    const float* __restrict__ x, const float* __restrict__ ow,
    const float* __restrict__ ob, unsigned int* __restrict__ po)
{
    __shared__ float wlds[KOFF][32][9];
    const int tid = threadIdx.x;
    const int p   = blockIdx.x * 256 + tid;
    const int b   = p / HW;
    const int rem = p % HW;
    const int y   = rem / WW;
    const int xx  = rem % WW;

    float acc[KOFF];
#pragma unroll
    for (int c = 0; c < KOFF; ++c) acc[c] = 0.f;

    for (int cb = 0; cb < CIN; cb += 32) {
        __syncthreads();
        for (int i = tid; i < KOFF * 32 * 9; i += 256) {
            int c  = i / 288;
            int r  = i % 288;
            int ci = r / 9;
            int t  = r % 9;
            wlds[c][ci][t] = ow[((size_t)c * CIN + cb + ci) * 9 + t];
        }
        __syncthreads();

        for (int ci = 0; ci < 32; ++ci) {
            const float* xp = x + ((size_t)(b * CIN + cb + ci)) * HW;
            float v[9];
#pragma unroll
            for (int dy = 0; dy < 3; ++dy) {
                int  yy  = y + dy - 1;
                bool yok = (unsigned)yy < HH;
#pragma unroll
                for (int dx = 0; dx < 3; ++dx) {
                    int  xw = xx + dx - 1;
                    bool ok = yok && ((unsigned)xw < WW);
                    v[dy * 3 + dx] = ok ? xp[yy * WW + xw] : 0.f;
                }
            }
#pragma unroll
            for (int c = 0; c < KOFF; ++c) {
                float a = acc[c];
#pragma unroll
                for (int t = 0; t < 9; ++t) a += v[t] * wlds[c][ci][t];
                acc[c] = a;
            }
        }
    }
#pragma unroll
    for (int s = 0; s < 9; ++s)
        po[(size_t)p * 9 + s] = (unsigned)f2bf(acc[s] + ob[s])
                              | ((unsigned)f2bf(acc[9 + s] + ob[9 + s]) << 16);
}

// ---------------------------------------------------------------------------
// Kernel 2: deformable sampling on NHWC bf16 -> NHWC bf16.
// Wave = 4 pixels x 16 ch-lanes (8 ch each). Per corner: one 16B vector load
// of 8 channels + 8 FMAs. 36 independent loads per thread, fully unrolled.
// ---------------------------------------------------------------------------
__global__ __launch_bounds__(256) void sample2_kernel(
    const unsigned short* __restrict__ xh, const unsigned int* __restrict__ po,
    unsigned short* __restrict__ sampled)
{
    const int tid  = threadIdx.x;
    const int lane = tid & 63;
    const int wave = tid >> 6;
    const int ppx  = lane >> 4;               // 0..3
    const int cl   = lane & 15;               // 0..15 -> channels cl*8..cl*8+7
    const int p    = blockIdx.x * 16 + wave * 4 + ppx;   // 6272 blocks * 16 == NPIX
    const int b    = p / HW;
    const int rem  = p % HW;
    const int y    = rem / WW;
    const int xx   = rem % WW;

    int   idx[9][4];
    float wt[9][4];
    const unsigned int* pop = po + (size_t)p * 9;
#pragma unroll
    for (int s = 0; s < 9; ++s) {
        const int ky = s / 3, kx = s % 3;
        const unsigned u = pop[s];
        const float oy = bflo(u);
        const float ox = bfhi(u);
        const float sy = (float)(y + ky - 1) + oy;
        const float sx = (float)(xx + kx - 1) + ox;
        const float y0f = floorf(sy), x0f = floorf(sx);
        const int   y0 = (int)y0f, x0 = (int)x0f;
        const float wy1 = sy - y0f, wx1 = sx - x0f;
        const float wy0 = 1.f - wy1, wx0 = 1.f - wx1;
        const int y0c = min(max(y0, 0), HH - 1), y1c = min(max(y0 + 1, 0), HH - 1);
        const int x0c = min(max(x0, 0), WW - 1), x1c = min(max(x0 + 1, 0), WW - 1);
        const bool vy0 = (unsigned)y0 < HH, vy1 = (unsigned)(y0 + 1) < HH;
        const bool vx0 = (unsigned)x0 < WW, vx1 = (unsigned)(x0 + 1) < WW;
        idx[s][0] = y0c * WW + x0c; wt[s][0] = (vy0 && vx0) ? wy0 * wx0 : 0.f;
        idx[s][1] = y0c * WW + x1c; wt[s][1] = (vy0 && vx1) ? wy0 * wx1 : 0.f;
        idx[s][2] = y1c * WW + x0c; wt[s][2] = (vy1 && vx0) ? wy1 * wx0 : 0.f;
        idx[s][3] = y1c * WW + x1c; wt[s][3] = (vy1 && vx1) ? wy1 * wx1 : 0.f;
    }

    const unsigned short* xb = xh + ((size_t)b * HW) * 128 + cl * 8;
    float acc[8];
#pragma unroll
    for (int j = 0; j < 8; ++j) acc[j] = 0.f;

#pragma unroll
    for (int s = 0; s < 9; ++s) {
#pragma unroll
        for (int c = 0; c < 4; ++c) {
            const uint4 v = *(const uint4*)(xb + (size_t)idx[s][c] * 128);
            const float w = wt[s][c];
            acc[0] += bflo(v.x) * w; acc[1] += bfhi(v.x) * w;
            acc[2] += bflo(v.y) * w; acc[3] += bfhi(v.y) * w;
            acc[4] += bflo(v.z) * w; acc[5] += bfhi(v.z) * w;
            acc[6] += bflo(v.w) * w; acc[7] += bfhi(v.w) * w;
        }
    }

    uint4 o;
    o.x = (unsigned)f2bf(acc[0]) | ((unsigned)f2bf(acc[1]) << 16);
    o.y = (unsigned)f2bf(acc[2]) | ((unsigned)f2bf(acc[3]) << 16);
    o.z = (unsigned)f2bf(acc[4]) | ((unsigned)f2bf(acc[5]) << 16);
    o.w = (unsigned)f2bf(acc[6]) | ((unsigned)f2bf(acc[7]) << 16);
    *(uint4*)(sampled + (size_t)p * 128 + cl * 8) = o;
}

// ---------------------------------------------------------------------------
// Kernel 3: implicit-GEMM 3x3 conv via bf16 MFMA (unchanged from round 2).
// ---------------------------------------------------------------------------
#define BK   64
#define LDR  (BK + 8)
__global__ __launch_bounds__(256) void conv_mfma_kernel(
    const unsigned short* __restrict__ sampled, const unsigned short* __restrict__ wt,
    float* __restrict__ out)
{
    __shared__ __align__(16) unsigned short As[128 * LDR];
    __shared__ __align__(16) unsigned short Bs[128 * LDR];

    const int tid = threadIdx.x;
    const int mb  = blockIdx.x;
    const int b   = mb / 98;
    const int p0  = (mb % 98) * 128;
    const int n0  = blockIdx.y * 128;

    const int srow  = tid >> 1;
    const int shalf = (tid & 1) * 32;
    const int pp  = p0 + srow;
    const int py  = pp / WW;
    const int pxx = pp % WW;

    const unsigned short* sb   = sampled + (size_t)b * HW * 128;
    const unsigned short* wrow = wt + (size_t)(n0 + srow) * 1152 + shalf;

    const int lane = tid & 63;
    const int wave = tid >> 6;
    const int wm   = (wave & 1) * 64;
    const int wn   = (wave >> 1) * 64;
    const int col  = lane & 15;
    const int quad = lane >> 4;

    f32x4 acc[4][4];
#pragma unroll
    for (int i = 0; i < 4; ++i)
#pragma unroll
        for (int j = 0; j < 4; ++j) acc[i][j] = (f32x4)0.f;

    for (int t = 0; t < 9; ++t) {
        const int dy = t / 3 - 1, dx = t % 3 - 1;
        const bool valid = ((unsigned)(py + dy) < HH) && ((unsigned)(pxx + dx) < WW);
        int q = pp + dy * WW + dx;
        q = min(max(q, 0), HW - 1);
        const unsigned short* arow = sb + (size_t)q * 128 + shalf;

        for (int ci0 = 0; ci0 < 128; ci0 += BK) {
            __syncthreads();
            {
                const uint4* src = (const uint4*)(arow + ci0);
                uint4* dst = (uint4*)(As + srow * LDR + shalf);
#pragma unroll
                for (int j = 0; j < 4; ++j) {
                    uint4 v = src[j];
                    if (!valid) { v.x = 0; v.y = 0; v.z = 0; v.w = 0; }
                    dst[j] = v;
                }
            }
            {
                const uint4* src = (const uint4*)(wrow + t * 128 + ci0);
                uint4* dst = (uint4*)(Bs + srow * LDR + shalf);
#pragma unroll
                for (int j = 0; j < 4; ++j) dst[j] = src[j];
            }
            __syncthreads();

#pragma unroll
            for (int kk = 0; kk < BK; kk += 32) {
                short8 af[4], bf[4];
#pragma unroll
                for (int f = 0; f < 4; ++f)
                    af[f] = *(const short8*)(As + (wm + f * 16 + col) * LDR + kk + quad * 8);
#pragma unroll
                for (int f = 0; f < 4; ++f)
                    bf[f] = *(const short8*)(Bs + (wn + f * 16 + col) * LDR + kk + quad * 8);
#pragma unroll
                for (int fm = 0; fm < 4; ++fm)
#pragma unroll
                    for (int fn = 0; fn < 4; ++fn)
                        acc[fm][fn] = __builtin_amdgcn_mfma_f32_16x16x32_bf16(
                            af[fm], bf[fn], acc[fm][fn], 0, 0, 0);
            }
        }
    }

#pragma unroll
    for (int fm = 0; fm < 4; ++fm) {
        const int pix = p0 + wm + fm * 16 + quad * 4;
#pragma unroll
        for (int fn = 0; fn < 4; ++fn) {
            const int co = n0 + wn + fn * 16 + col;
            float* op = out + ((size_t)(b * COUT + co)) * HW + pix;
            *(f32x4*)op = acc[fm][fn];
        }
    }
}

// ---------------------------------------------------------------------------
extern "C" void kernel_launch(void* const* d_in, const int* in_sizes, int n_in,
                              void* d_out, int out_size, void* d_ws, size_t ws_size,
                              hipStream_t stream)
{
    const float* x  = (const float*)d_in[0];   // (8,128,112,112)
    const float* ow = (const float*)d_in[1];   // (18,128,3,3)
    const float* ob = (const float*)d_in[2];   // (18,)
    const float* cw = (const float*)d_in[3];   // (256,128,3,3)
    float* out = (float*)d_out;                // (8,256,112,112)

    // workspace: po 3.6MB | sampled bf16 25.7MB | wt bf16 0.6MB | xh bf16 25.7MB
    unsigned int*   po      = (unsigned int*)d_ws;
    unsigned short* sampled = (unsigned short*)(po + (size_t)NPIX * 9);
    unsigned short* wtb     = sampled + (size_t)NPIX * 128;
    unsigned short* xh      = wtb + (size_t)COUT * 1152;

    wconvert_kernel<<<dim3(1152), dim3(256), 0, stream>>>(cw, wtb);
    nhwc_kernel<<<dim3(NPIX / 64), dim3(256), 0, stream>>>(x, xh);
    offset_conv_kernel<<<dim3(NPIX / 256), dim3(256), 0, stream>>>(x, ow, ob, po);
    sample2_kernel<<<dim3(NPIX / 16), dim3(256), 0, stream>>>(xh, po, sampled);
    conv_mfma_kernel<<<dim3(784, 2), dim3(256), 0, stream>>>(sampled, wtb, out);
}

// Round 4
// 315.454 us; speedup vs baseline: 6.0980x; 1.7204x over previous
//
#include <hip/hip_runtime.h>

// Problem constants
#define BATCH 8
#define CIN   128
#define HH    112
#define WW    112
#define COUT  256
#define KOFF  18          // 2*K*K offset channels
#define HW    (HH*WW)     // 12544
#define NPIX  (BATCH*HW)  // 100352

typedef __attribute__((ext_vector_type(8))) short short8;
typedef __attribute__((ext_vector_type(4))) float f32x4;

__device__ __forceinline__ unsigned short f2bf(float f) {
    union { float f; unsigned u; } v; v.f = f;
    unsigned r = v.u + 0x7fffu + ((v.u >> 16) & 1u);   // round-to-nearest-even
    return (unsigned short)(r >> 16);
}
__device__ __forceinline__ float bflo(unsigned u) {
    union { unsigned u; float f; } v; v.u = u << 16; return v.f;
}
__device__ __forceinline__ float bfhi(unsigned u) {
    union { unsigned u; float f; } v; v.u = u & 0xffff0000u; return v.f;
}

// ---------------------------------------------------------------------------
// Kernel 0a: main weights: wt[co][t*128+ci] = bf16(cw[co][ci][t])
// ---------------------------------------------------------------------------
__global__ __launch_bounds__(256) void wconvert_kernel(
    const float* __restrict__ cw, unsigned short* __restrict__ wt)
{
    const int i  = blockIdx.x * 256 + threadIdx.x;   // 1152*256 == 294912 exact
    const int co = i / 1152;
    const int k  = i % 1152;
    const int t  = k >> 7;
    const int ci = k & 127;
    wt[i] = f2bf(cw[((size_t)(co * CIN + ci)) * 9 + t]);
}

// ---------------------------------------------------------------------------
// Kernel 0b: offset weights, N padded 18->32: owt[co][t*128+ci], rows>=18 zero
// ---------------------------------------------------------------------------
__global__ __launch_bounds__(256) void owconvert_kernel(
    const float* __restrict__ ow, unsigned short* __restrict__ owt)
{
    const int i  = blockIdx.x * 256 + threadIdx.x;   // 144*256 == 36864 exact
    const int co = i / 1152;
    const int k  = i % 1152;
    const int t  = k >> 7;
    const int ci = k & 127;
    owt[i] = (co < KOFF) ? f2bf(ow[((size_t)(co * CIN + ci)) * 9 + t]) : 0;
}

// ---------------------------------------------------------------------------
// Kernel 0c: x NCHW fp32 -> NHWC bf16 (xh[p][128]) via LDS transpose.
// ---------------------------------------------------------------------------
__global__ __launch_bounds__(256) void nhwc_kernel(
    const float* __restrict__ x, unsigned short* __restrict__ xh)
{
    __shared__ unsigned int sm[64 * 65];
    const int tid = threadIdx.x;
    const int px  = tid & 63;
    const int cig = tid >> 6;
    const int p0  = blockIdx.x * 64;          // 1568 blocks; never straddles b
    const int b   = p0 / HW;
    const int rem0 = p0 % HW;
    const float* xb = x + (size_t)b * CIN * HW + rem0 + px;

    const int c0 = 2 * cig;
#pragma unroll
    for (int k = 0; k < 16; ++k) {
        const int ci = c0 + 8 * k;
        const float a0 = xb[(size_t)ci * HW];
        const float a1 = xb[(size_t)(ci + 1) * HW];
        sm[px * 65 + (ci >> 1)] = (unsigned)f2bf(a0) | ((unsigned)f2bf(a1) << 16);
    }
    __syncthreads();

    const int row = tid >> 2, chunk = tid & 3;
    unsigned int u[16];
#pragma unroll
    for (int c = 0; c < 16; ++c) u[c] = sm[row * 65 + chunk * 16 + c];
    uint4* gv = (uint4*)(xh + ((size_t)(p0 + row)) * 128 + chunk * 32);
#pragma unroll
    for (int j = 0; j < 4; ++j) {
        uint4 t; t.x = u[4*j]; t.y = u[4*j+1]; t.z = u[4*j+2]; t.w = u[4*j+3];
        gv[j] = t;
    }
}

#define BK   64
#define LDR  (BK + 8)     // LDS row stride (bf16 elems); 144 B, conflict-free frags

// ---------------------------------------------------------------------------
// Kernel 1: offset conv as implicit-GEMM MFMA. M=128 px, N=32 (18 used),
// K=1152. A from xh (tap-shifted, zero-masked); B = owt. D -> LDS -> packed
// bf16 (oy,ox) pairs po[p*9+s], bias added in fp32.
// ---------------------------------------------------------------------------
__global__ __launch_bounds__(256) void offset_mfma_kernel(
    const unsigned short* __restrict__ xh, const unsigned short* __restrict__ owt,
    const float* __restrict__ ob, unsigned int* __restrict__ po)
{
    __shared__ __align__(16) unsigned short As[128 * LDR];   // 18.4 KB
    __shared__ __align__(16) unsigned short Bs[32 * LDR];    // 4.6 KB
    __shared__ float sm_off[128][20];                        // 10.2 KB
    __shared__ float sb_bias[KOFF];

    const int tid = threadIdx.x;
    const int mb  = blockIdx.x;          // 784 blocks (98/image)
    const int b   = mb / 98;
    const int p0  = (mb % 98) * 128;     // within-image pixel base

    if (tid < KOFF) sb_bias[tid] = ob[tid];

    const int srow  = tid >> 1;
    const int shalf = (tid & 1) * 32;
    const int pp  = p0 + srow;
    const int py  = pp / WW;
    const int pxx = pp % WW;

    const unsigned short* xb = xh + (size_t)b * HW * 128;

    const int lane = tid & 63;
    const int wave = tid >> 6;
    const int col  = lane & 15;
    const int quad = lane >> 4;
    const int m0   = wave * 32;          // wave owns 32 M-rows, all 32 N-cols

    f32x4 acc[2][2];
#pragma unroll
    for (int i = 0; i < 2; ++i)
#pragma unroll
        for (int j = 0; j < 2; ++j) acc[i][j] = (f32x4)0.f;

    for (int t = 0; t < 9; ++t) {
        const int dy = t / 3 - 1, dx = t % 3 - 1;
        const bool valid = ((unsigned)(py + dy) < HH) && ((unsigned)(pxx + dx) < WW);
        int q = pp + dy * WW + dx;
        q = min(max(q, 0), HW - 1);
        const unsigned short* arow = xb + (size_t)q * 128 + shalf;

        for (int ci0 = 0; ci0 < 128; ci0 += BK) {
            __syncthreads();
            {
                const uint4* src = (const uint4*)(arow + ci0);
                uint4* dst = (uint4*)(As + srow * LDR + shalf);
#pragma unroll
                for (int j = 0; j < 4; ++j) {
                    uint4 v = src[j];
                    if (!valid) { v.x = 0; v.y = 0; v.z = 0; v.w = 0; }
                    dst[j] = v;
                }
            }
            if (tid < 64) {
                const int brow = tid >> 1, bh = (tid & 1) * 32;
                const uint4* src = (const uint4*)(owt + (size_t)brow * 1152 + t * 128 + ci0 + bh);
                uint4* dst = (uint4*)(Bs + brow * LDR + bh);
#pragma unroll
                for (int j = 0; j < 4; ++j) dst[j] = src[j];
            }
            __syncthreads();

#pragma unroll
            for (int kk = 0; kk < BK; kk += 32) {
                short8 af[2], bfr[2];
#pragma unroll
                for (int f = 0; f < 2; ++f)
                    af[f] = *(const short8*)(As + (m0 + f * 16 + col) * LDR + kk + quad * 8);
#pragma unroll
                for (int f = 0; f < 2; ++f)
                    bfr[f] = *(const short8*)(Bs + (f * 16 + col) * LDR + kk + quad * 8);
#pragma unroll
                for (int fm = 0; fm < 2; ++fm)
#pragma unroll
                    for (int fn = 0; fn < 2; ++fn)
                        acc[fm][fn] = __builtin_amdgcn_mfma_f32_16x16x32_bf16(
                            af[fm], bfr[fn], acc[fm][fn], 0, 0, 0);
            }
        }
    }

    // D (row = m0+fm*16+quad*4+r, col = fn*16+(lane&15)) -> LDS
#pragma unroll
    for (int fm = 0; fm < 2; ++fm)
#pragma unroll
        for (int fn = 0; fn < 2; ++fn) {
            const int c = fn * 16 + col;
            if (c < KOFF) {
                const int rb = m0 + fm * 16 + quad * 4;
#pragma unroll
                for (int r = 0; r < 4; ++r) sm_off[rb + r][c] = acc[fm][fn][r];
            }
        }
    __syncthreads();

    if (tid < 128) {
        unsigned int* pop = po + ((size_t)(b * HW + p0 + tid)) * 9;
#pragma unroll
        for (int s = 0; s < 9; ++s) {
            const float oy = sm_off[tid][s]     + sb_bias[s];
            const float ox = sm_off[tid][9 + s] + sb_bias[9 + s];
            pop[s] = (unsigned)f2bf(oy) | ((unsigned)f2bf(ox) << 16);
        }
    }
}

// ---------------------------------------------------------------------------
// Kernel 2: deformable sampling on NHWC bf16 -> NHWC bf16 (unchanged).
// ---------------------------------------------------------------------------
__global__ __launch_bounds__(256) void sample2_kernel(
    const unsigned short* __restrict__ xh, const unsigned int* __restrict__ po,
    unsigned short* __restrict__ sampled)
{
    const int tid  = threadIdx.x;
    const int lane = tid & 63;
    const int wave = tid >> 6;
    const int ppx  = lane >> 4;
    const int cl   = lane & 15;
    const int p    = blockIdx.x * 16 + wave * 4 + ppx;   // 6272 blocks * 16 == NPIX
    const int b    = p / HW;
    const int rem  = p % HW;
    const int y    = rem / WW;
    const int xx   = rem % WW;

    int   idx[9][4];
    float wt[9][4];
    const unsigned int* pop = po + (size_t)p * 9;
#pragma unroll
    for (int s = 0; s < 9; ++s) {
        const int ky = s / 3, kx = s % 3;
        const unsigned u = pop[s];
        const float oy = bflo(u);
        const float ox = bfhi(u);
        const float sy = (float)(y + ky - 1) + oy;
        const float sx = (float)(xx + kx - 1) + ox;
        const float y0f = floorf(sy), x0f = floorf(sx);
        const int   y0 = (int)y0f, x0 = (int)x0f;
        const float wy1 = sy - y0f, wx1 = sx - x0f;
        const float wy0 = 1.f - wy1, wx0 = 1.f - wx1;
        const int y0c = min(max(y0, 0), HH - 1), y1c = min(max(y0 + 1, 0), HH - 1);
        const int x0c = min(max(x0, 0), WW - 1), x1c = min(max(x0 + 1, 0), WW - 1);
        const bool vy0 = (unsigned)y0 < HH, vy1 = (unsigned)(y0 + 1) < HH;
        const bool vx0 = (unsigned)x0 < WW, vx1 = (unsigned)(x0 + 1) < WW;
        idx[s][0] = y0c * WW + x0c; wt[s][0] = (vy0 && vx0) ? wy0 * wx0 : 0.f;
        idx[s][1] = y0c * WW + x1c; wt[s][1] = (vy0 && vx1) ? wy0 * wx1 : 0.f;
        idx[s][2] = y1c * WW + x0c; wt[s][2] = (vy1 && vx0) ? wy1 * wx0 : 0.f;
        idx[s][3] = y1c * WW + x1c; wt[s][3] = (vy1 && vx1) ? wy1 * wx1 : 0.f;
    }

    const unsigned short* xb = xh + ((size_t)b * HW) * 128 + cl * 8;
    float acc[8];
#pragma unroll
    for (int j = 0; j < 8; ++j) acc[j] = 0.f;

#pragma unroll
    for (int s = 0; s < 9; ++s) {
#pragma unroll
        for (int c = 0; c < 4; ++c) {
            const uint4 v = *(const uint4*)(xb + (size_t)idx[s][c] * 128);
            const float w = wt[s][c];
            acc[0] += bflo(v.x) * w; acc[1] += bfhi(v.x) * w;
            acc[2] += bflo(v.y) * w; acc[3] += bfhi(v.y) * w;
            acc[4] += bflo(v.z) * w; acc[5] += bfhi(v.z) * w;
            acc[6] += bflo(v.w) * w; acc[7] += bfhi(v.w) * w;
        }
    }

    uint4 o;
    o.x = (unsigned)f2bf(acc[0]) | ((unsigned)f2bf(acc[1]) << 16);
    o.y = (unsigned)f2bf(acc[2]) | ((unsigned)f2bf(acc[3]) << 16);
    o.z = (unsigned)f2bf(acc[4]) | ((unsigned)f2bf(acc[5]) << 16);
    o.w = (unsigned)f2bf(acc[6]) | ((unsigned)f2bf(acc[7]) << 16);
    *(uint4*)(sampled + (size_t)p * 128 + cl * 8) = o;
}

// ---------------------------------------------------------------------------
// Kernel 3: implicit-GEMM 3x3 conv via bf16 MFMA (unchanged from round 2).
// ---------------------------------------------------------------------------
__global__ __launch_bounds__(256) void conv_mfma_kernel(
    const unsigned short* __restrict__ sampled, const unsigned short* __restrict__ wt,
    float* __restrict__ out)
{
    __shared__ __align__(16) unsigned short As[128 * LDR];
    __shared__ __align__(16) unsigned short Bs[128 * LDR];

    const int tid = threadIdx.x;
    const int mb  = blockIdx.x;
    const int b   = mb / 98;
    const int p0  = (mb % 98) * 128;
    const int n0  = blockIdx.y * 128;

    const int srow  = tid >> 1;
    const int shalf = (tid & 1) * 32;
    const int pp  = p0 + srow;
    const int py  = pp / WW;
    const int pxx = pp % WW;

    const unsigned short* sb   = sampled + (size_t)b * HW * 128;
    const unsigned short* wrow = wt + (size_t)(n0 + srow) * 1152 + shalf;

    const int lane = tid & 63;
    const int wave = tid >> 6;
    const int wm   = (wave & 1) * 64;
    const int wn   = (wave >> 1) * 64;
    const int col  = lane & 15;
    const int quad = lane >> 4;

    f32x4 acc[4][4];
#pragma unroll
    for (int i = 0; i < 4; ++i)
#pragma unroll
        for (int j = 0; j < 4; ++j) acc[i][j] = (f32x4)0.f;

    for (int t = 0; t < 9; ++t) {
        const int dy = t / 3 - 1, dx = t % 3 - 1;
        const bool valid = ((unsigned)(py + dy) < HH) && ((unsigned)(pxx + dx) < WW);
        int q = pp + dy * WW + dx;
        q = min(max(q, 0), HW - 1);
        const unsigned short* arow = sb + (size_t)q * 128 + shalf;

        for (int ci0 = 0; ci0 < 128; ci0 += BK) {
            __syncthreads();
            {
                const uint4* src = (const uint4*)(arow + ci0);
                uint4* dst = (uint4*)(As + srow * LDR + shalf);
#pragma unroll
                for (int j = 0; j < 4; ++j) {
                    uint4 v = src[j];
                    if (!valid) { v.x = 0; v.y = 0; v.z = 0; v.w = 0; }
                    dst[j] = v;
                }
            }
            {
                const uint4* src = (const uint4*)(wrow + t * 128 + ci0);
                uint4* dst = (uint4*)(Bs + srow * LDR + shalf);
#pragma unroll
                for (int j = 0; j < 4; ++j) dst[j] = src[j];
            }
            __syncthreads();

#pragma unroll
            for (int kk = 0; kk < BK; kk += 32) {
                short8 af[4], bf[4];
#pragma unroll
                for (int f = 0; f < 4; ++f)
                    af[f] = *(const short8*)(As + (wm + f * 16 + col) * LDR + kk + quad * 8);
#pragma unroll
                for (int f = 0; f < 4; ++f)
                    bf[f] = *(const short8*)(Bs + (wn + f * 16 + col) * LDR + kk + quad * 8);
#pragma unroll
                for (int fm = 0; fm < 4; ++fm)
#pragma unroll
                    for (int fn = 0; fn < 4; ++fn)
                        acc[fm][fn] = __builtin_amdgcn_mfma_f32_16x16x32_bf16(
                            af[fm], bf[fn], acc[fm][fn], 0, 0, 0);
            }
        }
    }

#pragma unroll
    for (int fm = 0; fm < 4; ++fm) {
        const int pix = p0 + wm + fm * 16 + quad * 4;
#pragma unroll
        for (int fn = 0; fn < 4; ++fn) {
            const int co = n0 + wn + fn * 16 + col;
            float* op = out + ((size_t)(b * COUT + co)) * HW + pix;
            *(f32x4*)op = acc[fm][fn];
        }
    }
}

// ---------------------------------------------------------------------------
extern "C" void kernel_launch(void* const* d_in, const int* in_sizes, int n_in,
                              void* d_out, int out_size, void* d_ws, size_t ws_size,
                              hipStream_t stream)
{
    const float* x  = (const float*)d_in[0];   // (8,128,112,112)
    const float* ow = (const float*)d_in[1];   // (18,128,3,3)
    const float* ob = (const float*)d_in[2];   // (18,)
    const float* cw = (const float*)d_in[3];   // (256,128,3,3)
    float* out = (float*)d_out;                // (8,256,112,112)

    // ws: po 3.6MB | sampled 25.7MB | wt 0.59MB | xh 25.7MB | owt 74KB  (~55.8MB)
    unsigned int*   po      = (unsigned int*)d_ws;
    unsigned short* sampled = (unsigned short*)(po + (size_t)NPIX * 9);
    unsigned short* wtb     = sampled + (size_t)NPIX * 128;
    unsigned short* xh      = wtb + (size_t)COUT * 1152;
    unsigned short* owt     = xh + (size_t)NPIX * 128;

    wconvert_kernel<<<dim3(1152), dim3(256), 0, stream>>>(cw, wtb);
    owconvert_kernel<<<dim3(144), dim3(256), 0, stream>>>(ow, owt);
    nhwc_kernel<<<dim3(NPIX / 64), dim3(256), 0, stream>>>(x, xh);
    offset_mfma_kernel<<<dim3(784), dim3(256), 0, stream>>>(xh, owt, ob, po);
    sample2_kernel<<<dim3(NPIX / 16), dim3(256), 0, stream>>>(xh, po, sampled);
    conv_mfma_kernel<<<dim3(784, 2), dim3(256), 0, stream>>>(sampled, wtb, out);
}